// Round 1
// baseline (56.855 us; speedup 1.0000x reference)
//
#include <hip/hip_runtime.h>
#include <math.h>

#define NB 32
#define NH 128
#define NW 128
#define NC 3
#define NF 2
#define NQ 9
#define NL 2
#define I0 126
#define I1 126
#define NPIX (NB * I0 * I1)

// Table layout: for t = (f*NC + c)*NQ + q, 8 floats:
// [w_enc, Rs.x, Rs.y, Rs.z, Rc.x, Rc.y, Rc.z, pad]
__global__ void precompute_tab(const float* __restrict__ w_enc,
                               const float* __restrict__ a_rz,
                               const float* __restrict__ b_ry,
                               float* __restrict__ tab) {
    int t = threadIdx.x;
    if (t >= NF * NC * NQ) return;
    int f = t / (NC * NQ);
    int c = (t / NQ) % NC;
    int q = t % NQ;

    // track images of e0 (u) and e2 (w) through the rotation chain
    float ux = 1.f, uy = 0.f, uz = 0.f;
    float wx = 0.f, wy = 0.f, wz = 1.f;
    for (int l = 0; l < NL; ++l) {
        int ia = ((f * NC + c) * NL + l) * NQ + q;
        float av = a_rz[ia], bv = b_ry[ia];
        float ca = cosf(av), sa = sinf(av);
        float cb = cosf(bv), sb = sinf(bv);
        float nx, ny, nz;
        // Rz(a): (x,y) -> (x*ca - y*sa, x*sa + y*ca)
        nx = ux * ca - uy * sa; ny = ux * sa + uy * ca; ux = nx; uy = ny;
        // Ry(b): (x,z) -> (x*cb + z*sb, -x*sb + z*cb)   [uses NEW x]
        nx = ux * cb + uz * sb; nz = -ux * sb + uz * cb; ux = nx; uz = nz;

        nx = wx * ca - wy * sa; ny = wx * sa + wy * ca; wx = nx; wy = ny;
        nx = wx * cb + wz * sb; nz = -wx * sb + wz * cb; wx = nx; wz = nz;
    }
    float* o = tab + t * 8;
    o[0] = w_enc[t];   // w_enc flat index (f*NC+c)*NQ+q == t
    o[1] = ux; o[2] = uy; o[3] = uz;
    o[4] = wx; o[5] = wy; o[6] = wz;
    o[7] = 0.f;
}

__global__ __launch_bounds__(256) void qconv_main(
        const float* __restrict__ x,
        const float* __restrict__ tab,
        float* __restrict__ out) {
    __shared__ float stab[NF * NC * NQ * 8];
    for (int i = threadIdx.x; i < NF * NC * NQ * 8; i += blockDim.x)
        stab[i] = tab[i];
    __syncthreads();

    int pix = blockIdx.x * blockDim.x + threadIdx.x;
    if (pix >= NPIX) return;
    int j = pix % I1;
    int i = (pix / I1) % I0;
    int b = pix / (I1 * I0);

    // patch rows: x[b, i+di, j : j+3, :] = 9 contiguous floats each
    float p[3][9];
#pragma unroll
    for (int di = 0; di < 3; ++di) {
        const float* row = x + ((size_t)(b * NH + i + di) * NW + j) * NC;
#pragma unroll
        for (int k = 0; k < 9; ++k) p[di][k] = row[k];
    }

    float outv[NF * NQ * 3];
#pragma unroll
    for (int f = 0; f < NF; ++f) {
#pragma unroll
        for (int q = 0; q < NQ; ++q) {
            int di = q / 3, dj = q % 3;
            float a0 = 0.f, a1 = 0.f, a2 = 0.f;
#pragma unroll
            for (int c = 0; c < NC; ++c) {
                const float* cf = &stab[(size_t)((f * NC + c) * NQ + q) * 8];
                float theta = p[di][dj * 3 + c] * cf[0];
                float s, co;
                __sincosf(theta, &s, &co);
                a0 += cf[1] * s + cf[4] * co;
                a1 += cf[2] * s + cf[5] * co;
                a2 += cf[3] * s + cf[6] * co;
            }
            int base = (f * NQ + q) * 3;
            outv[base + 0] = fmaxf(a0, 0.f);
            outv[base + 1] = fmaxf(a1, 0.f);
            outv[base + 2] = fmaxf(a2, 0.f);
        }
    }

    float* op = out + (size_t)pix * (NF * NQ * 3);
#pragma unroll
    for (int k = 0; k < 27; ++k) {
        reinterpret_cast<float2*>(op)[k] = make_float2(outv[2 * k], outv[2 * k + 1]);
    }
}

extern "C" void kernel_launch(void* const* d_in, const int* in_sizes, int n_in,
                              void* d_out, int out_size, void* d_ws, size_t ws_size,
                              hipStream_t stream) {
    const float* x     = (const float*)d_in[0];
    const float* w_enc = (const float*)d_in[1];
    const float* a_rz  = (const float*)d_in[2];
    const float* b_ry  = (const float*)d_in[3];
    float* out = (float*)d_out;
    float* tab = (float*)d_ws;   // 54*8*4 = 1728 B

    precompute_tab<<<1, 64, 0, stream>>>(w_enc, a_rz, b_ry, tab);

    int total = NPIX;
    int block = 256;
    int grid = (total + block - 1) / block;
    qconv_main<<<grid, block, 0, stream>>>(x, tab, out);
}

// Round 2
// 43.027 us; speedup vs baseline: 1.3214x; 1.3214x over previous
//
#include <hip/hip_runtime.h>
#include <math.h>

#define NB 32
#define NH 128
#define NW 128
#define NC 3
#define NF 2
#define NQ 9
#define NL 2
#define I0 126
#define I1 126
#define NPIX (NB * I0 * I1)
#define NWORK (NPIX * 18)   // 18 = NF*NQ work items per pixel

// Table layout: for t = (f*NC + c)*NQ + q, 8 floats:
// [w_enc, Rs.x, Rs.y, Rs.z, Rc.x, Rc.y, Rc.z, pad]
__global__ void precompute_tab(const float* __restrict__ w_enc,
                               const float* __restrict__ a_rz,
                               const float* __restrict__ b_ry,
                               float* __restrict__ tab) {
    int t = threadIdx.x;
    if (t >= NF * NC * NQ) return;
    int f = t / (NC * NQ);
    int c = (t / NQ) % NC;
    int q = t % NQ;

    // track images of e0 (u) and e2 (w) through the rotation chain
    float ux = 1.f, uy = 0.f, uz = 0.f;
    float wx = 0.f, wy = 0.f, wz = 1.f;
    for (int l = 0; l < NL; ++l) {
        int ia = ((f * NC + c) * NL + l) * NQ + q;
        float av = a_rz[ia], bv = b_ry[ia];
        float ca = cosf(av), sa = sinf(av);
        float cb = cosf(bv), sb = sinf(bv);
        float nx, ny, nz;
        // Rz(a): (x,y) -> (x*ca - y*sa, x*sa + y*ca)
        nx = ux * ca - uy * sa; ny = ux * sa + uy * ca; ux = nx; uy = ny;
        // Ry(b): (x,z) -> (x*cb + z*sb, -x*sb + z*cb)   [uses NEW x]
        nx = ux * cb + uz * sb; nz = -ux * sb + uz * cb; ux = nx; uz = nz;

        nx = wx * ca - wy * sa; ny = wx * sa + wy * ca; wx = nx; wy = ny;
        nx = wx * cb + wz * sb; nz = -wx * sb + wz * cb; wx = nx; wz = nz;
    }
    float* o = tab + t * 8;
    o[0] = w_enc[t];
    o[1] = ux; o[2] = uy; o[3] = uz;
    o[4] = wx; o[5] = wy; o[6] = wz;
    o[7] = 0.f;
}

struct f3 { float x, y, z; };   // plain 4B-aligned triple -> global_store_dwordx3

__global__ __launch_bounds__(256) void qconv_main(
        const float* __restrict__ x,
        const float* __restrict__ tab,
        float* __restrict__ out) {
    __shared__ float stab[NF * NC * NQ * 8];
    for (int i = threadIdx.x; i < NF * NC * NQ * 8; i += blockDim.x)
        stab[i] = tab[i];
    __syncthreads();

    int T = blockIdx.x * blockDim.x + threadIdx.x;   // NWORK divisible by 256
    int q18 = T % 18;            // f*9 + q
    int pix = T / 18;
    int f = q18 / 9;
    int q = q18 % 9;
    int j = pix % I1;
    int i = (pix / I1) % I0;
    int b = pix / (I1 * I0);

    int di = q / 3, dj = q % 3;
    const float* px = x + ((size_t)((b * NH + i + di) * NW) + (j + dj)) * NC;
    float p0 = px[0], p1 = px[1], p2 = px[2];

    float a0 = 0.f, a1 = 0.f, a2 = 0.f;
#pragma unroll
    for (int c = 0; c < NC; ++c) {
        const float* cf = &stab[(size_t)((f * NC + c) * NQ + q) * 8];
        float pc = (c == 0) ? p0 : (c == 1) ? p1 : p2;
        float theta = pc * cf[0];
        float s, co;
        __sincosf(theta, &s, &co);
        a0 += cf[1] * s + cf[4] * co;
        a1 += cf[2] * s + cf[5] * co;
        a2 += cf[3] * s + cf[6] * co;
    }

    f3 r;
    r.x = fmaxf(a0, 0.f);
    r.y = fmaxf(a1, 0.f);
    r.z = fmaxf(a2, 0.f);
    // out element index = pix*54 + q18*3 == T*3  -> dense 12B/lane stream
    *reinterpret_cast<f3*>(out + (size_t)T * 3) = r;
}

extern "C" void kernel_launch(void* const* d_in, const int* in_sizes, int n_in,
                              void* d_out, int out_size, void* d_ws, size_t ws_size,
                              hipStream_t stream) {
    const float* x     = (const float*)d_in[0];
    const float* w_enc = (const float*)d_in[1];
    const float* a_rz  = (const float*)d_in[2];
    const float* b_ry  = (const float*)d_in[3];
    float* out = (float*)d_out;
    float* tab = (float*)d_ws;   // 54*8*4 = 1728 B

    precompute_tab<<<1, 64, 0, stream>>>(w_enc, a_rz, b_ry, tab);

    int block = 256;
    int grid = NWORK / block;    // exact: 9,144,576 / 256 = 35,721
    qconv_main<<<grid, block, 0, stream>>>(x, tab, out);
}

// Round 3
// 32.471 us; speedup vs baseline: 1.7509x; 1.3251x over previous
//
#include <hip/hip_runtime.h>
#include <math.h>

#define NB 32
#define NH 128
#define NW 128
#define NC 3
#define NF 2
#define NQ 9
#define NL 2
#define I0 126
#define I1 126
#define NPIX (NB * I0 * I1)          // 508,032
#define NWORK (NPIX * 18)            // 9,144,576
#define GTHREADS 1016064             // 3969 blocks * 256; NWORK / 9
#define DPIX 56448                   // GTHREADS / 18 pixels advanced per iter
#define NITER 9                      // DPIX * NITER == NPIX exactly

// Table layout: for t = (f*NC + c)*NQ + q, 8 floats:
// [w_enc, Rs.x, Rs.y, Rs.z, Rc.x, Rc.y, Rc.z, pad]
__global__ void precompute_tab(const float* __restrict__ w_enc,
                               const float* __restrict__ a_rz,
                               const float* __restrict__ b_ry,
                               float* __restrict__ tab) {
    int t = threadIdx.x;
    if (t >= NF * NC * NQ) return;
    int f = t / (NC * NQ);
    int c = (t / NQ) % NC;
    int q = t % NQ;

    float ux = 1.f, uy = 0.f, uz = 0.f;   // image of e0
    float wx = 0.f, wy = 0.f, wz = 1.f;   // image of e2
    for (int l = 0; l < NL; ++l) {
        int ia = ((f * NC + c) * NL + l) * NQ + q;
        float av = a_rz[ia], bv = b_ry[ia];
        float ca = cosf(av), sa = sinf(av);
        float cb = cosf(bv), sb = sinf(bv);
        float nx, ny, nz;
        nx = ux * ca - uy * sa; ny = ux * sa + uy * ca; ux = nx; uy = ny;
        nx = ux * cb + uz * sb; nz = -ux * sb + uz * cb; ux = nx; uz = nz;

        nx = wx * ca - wy * sa; ny = wx * sa + wy * ca; wx = nx; wy = ny;
        nx = wx * cb + wz * sb; nz = -wx * sb + wz * cb; wx = nx; wz = nz;
    }
    float* o = tab + t * 8;
    o[0] = w_enc[t];
    o[1] = ux; o[2] = uy; o[3] = uz;
    o[4] = wx; o[5] = wy; o[6] = wz;
    o[7] = 0.f;
}

struct f3 { float x, y, z; };   // 4B-aligned triple -> dwordx3

__global__ __launch_bounds__(256) void qconv_main(
        const float* __restrict__ x,
        const float* __restrict__ tab,
        float* __restrict__ out) {
    int T0 = blockIdx.x * 256 + threadIdx.x;     // < GTHREADS
    int pixb = T0 / 18;
    int q18 = T0 - pixb * 18;
    int f = (q18 >= 9) ? 1 : 0;
    int q = q18 - f * 9;
    int di = q / 3, dj = q - di * 3;

    // one-time: pull this thread's 21 coefficients into registers
    float cw[3], sx[3], sy[3], sz[3], cx[3], cy[3], cz[3];
#pragma unroll
    for (int c = 0; c < 3; ++c) {
        const float* r = tab + (size_t)(f * 27 + c * 9 + q) * 8;
        float4 v0 = *reinterpret_cast<const float4*>(r);
        float4 v1 = *reinterpret_cast<const float4*>(r + 4);
        cw[c] = v0.x; sx[c] = v0.y; sy[c] = v0.z; sz[c] = v0.w;
        cx[c] = v1.x; cy[c] = v1.y; cz[c] = v1.z;
    }

    // one-time pixel decode
    int b   = pixb / (I0 * I1);
    int rem = pixb - b * (I0 * I1);
    int i   = rem / I1;
    int j   = rem - i * I1;

    int  icur   = i;
    long rowidx = (long)b * NH + i + di;          // input row
    long outidx = (long)pixb * 54 + q18 * 3;      // output float index
    int  jcol   = j + dj;

    // per-iter constants: pix += DPIX == b+=3, i+=70 (wrap: extra b+=1)
    for (int it = 0; it < NITER; ++it) {
        const float* px = x + ((size_t)rowidx * NW + jcol) * NC;
        float p0 = px[0], p1 = px[1], p2 = px[2];

        float a0 = 0.f, a1 = 0.f, a2 = 0.f;
#pragma unroll
        for (int c = 0; c < 3; ++c) {
            float pc = (c == 0) ? p0 : (c == 1) ? p1 : p2;
            float s, co;
            __sincosf(pc * cw[c], &s, &co);
            a0 = fmaf(sx[c], s, fmaf(cx[c], co, a0));
            a1 = fmaf(sy[c], s, fmaf(cy[c], co, a1));
            a2 = fmaf(sz[c], s, fmaf(cz[c], co, a2));
        }

        f3 r;
        r.x = fmaxf(a0, 0.f);
        r.y = fmaxf(a1, 0.f);
        r.z = fmaxf(a2, 0.f);
        *reinterpret_cast<f3*>(out + outidx) = r;

        // advance by DPIX pixels: delta rows = 3*128 + 70 = 454 (456 on i-wrap)
        icur += 70;
        rowidx += 454;
        if (icur >= I0) { icur -= I0; rowidx += 2; }
        outidx += (long)DPIX * 54;
    }
}

extern "C" void kernel_launch(void* const* d_in, const int* in_sizes, int n_in,
                              void* d_out, int out_size, void* d_ws, size_t ws_size,
                              hipStream_t stream) {
    const float* x     = (const float*)d_in[0];
    const float* w_enc = (const float*)d_in[1];
    const float* a_rz  = (const float*)d_in[2];
    const float* b_ry  = (const float*)d_in[3];
    float* out = (float*)d_out;
    float* tab = (float*)d_ws;   // 54*8*4 = 1728 B

    precompute_tab<<<1, 64, 0, stream>>>(w_enc, a_rz, b_ry, tab);

    int block = 256;
    int grid = GTHREADS / block;   // 3969
    qconv_main<<<grid, block, 0, stream>>>(x, tab, out);
}

// Round 4
// 26.933 us; speedup vs baseline: 2.1110x; 1.2056x over previous
//
#include <hip/hip_runtime.h>
#include <math.h>

#define NB 32
#define NH 128
#define NW 128
#define NC 3
#define NF 2
#define NQ 9
#define NL 2
#define I0 126
#define I1 126
#define NPIX (NB * I0 * I1)          // 508,032
#define NWORK (NPIX * 18)            // 9,144,576
#define GTHREADS 1016064             // 3969 blocks * 256; NWORK / 9
#define DPIX 56448                   // GTHREADS / 18 pixels advanced per iter
#define INV2PI 0.15915494309189535f

struct f3 { float x, y, z; };        // 4B-aligned triple -> dwordx3

__global__ __launch_bounds__(256) void qconv_fused(
        const float* __restrict__ x,
        const float* __restrict__ w_enc,
        const float* __restrict__ a_rz,
        const float* __restrict__ b_ry,
        float* __restrict__ out) {
    // ---- per-block coefficient table build (threads 0..53) ----
    // row t = f*27 + c*9 + q : [w*inv2pi, Rs.x,Rs.y,Rs.z, Rc.x,Rc.y,Rc.z, pad]
    __shared__ float stab[54 * 8];
    int tid = threadIdx.x;
    if (tid < 54) {
        int t = tid;
        int f = t / 27;
        int c = (t / 9) % 3;
        int q = t % 9;
        float ux = 1.f, uy = 0.f, uz = 0.f;   // image of e0
        float wx = 0.f, wy = 0.f, wz = 1.f;   // image of e2
#pragma unroll
        for (int l = 0; l < NL; ++l) {
            int ia = ((f * NC + c) * NL + l) * NQ + q;
            float sa, ca, sb, cb;
            __sincosf(a_rz[ia], &sa, &ca);
            __sincosf(b_ry[ia], &sb, &cb);
            float nx, ny, nz;
            nx = ux * ca - uy * sa; ny = ux * sa + uy * ca; ux = nx; uy = ny;
            nx = ux * cb + uz * sb; nz = -ux * sb + uz * cb; ux = nx; uz = nz;
            nx = wx * ca - wy * sa; ny = wx * sa + wy * ca; wx = nx; wy = ny;
            nx = wx * cb + wz * sb; nz = -wx * sb + wz * cb; wx = nx; wz = nz;
        }
        float* o = stab + t * 8;
        o[0] = w_enc[t] * INV2PI;
        o[1] = ux; o[2] = uy; o[3] = uz;
        o[4] = wx; o[5] = wy; o[6] = wz;
        o[7] = 0.f;
    }
    __syncthreads();

    // ---- per-thread setup ----
    int T0 = blockIdx.x * 256 + tid;             // < GTHREADS
    int pixb = T0 / 18;
    int q18 = T0 - pixb * 18;
    int f = (q18 >= 9) ? 1 : 0;
    int q = q18 - f * 9;
    int di = q / 3, dj = q - di * 3;

    float cw[3], sx[3], sy[3], sz[3], cx[3], cy[3], cz[3];
#pragma unroll
    for (int c = 0; c < 3; ++c) {
        const float* r = stab + (size_t)(f * 27 + c * 9 + q) * 8;
        float4 v0 = *reinterpret_cast<const float4*>(r);
        float4 v1 = *reinterpret_cast<const float4*>(r + 4);
        cw[c] = v0.x; sx[c] = v0.y; sy[c] = v0.z; sz[c] = v0.w;
        cx[c] = v1.x; cy[c] = v1.y; cz[c] = v1.z;
    }

    int b   = pixb / (I0 * I1);
    int rem = pixb - b * (I0 * I1);
    int i   = rem / I1;
    int j   = rem - i * I1;

    int icur = i;
    const float* pin = x + ((size_t)((b * NH + i + di) * NW) + (j + dj)) * NC;
    float* pout = out + (size_t)pixb * 54 + q18 * 3;

    const long STEP_IN  = 454L * NW * NC;        // +DPIX pixels: 454 rows
    const long WRAP_IN  = 2L * NW * NC;          // i-wrap: +2 rows extra
    const long STEP_OUT = (long)DPIX * 54;

#define ADVANCE()  do { icur += 70; pin += STEP_IN; \
                        if (icur >= I0) { icur -= I0; pin += WRAP_IN; } } while (0)

#define COMPUTE_STORE(P, OP) do {                                   \
        float a0 = 0.f, a1 = 0.f, a2 = 0.f;                         \
        _Pragma("unroll")                                           \
        for (int c = 0; c < 3; ++c) {                               \
            float pc = (c == 0) ? (P).x : (c == 1) ? (P).y : (P).z; \
            float xr = pc * cw[c];                                  \
            float s  = __builtin_amdgcn_sinf(xr);                   \
            float co = __builtin_amdgcn_cosf(xr);                   \
            a0 = fmaf(sx[c], s, fmaf(cx[c], co, a0));               \
            a1 = fmaf(sy[c], s, fmaf(cy[c], co, a1));               \
            a2 = fmaf(sz[c], s, fmaf(cz[c], co, a2));               \
        }                                                           \
        f3 r_;                                                      \
        r_.x = fmaxf(a0, 0.f);                                      \
        r_.y = fmaxf(a1, 0.f);                                      \
        r_.z = fmaxf(a2, 0.f);                                      \
        *reinterpret_cast<f3*>(OP) = r_;                            \
    } while (0)

#pragma unroll
    for (int g = 0; g < 3; ++g) {
        const float* pA = pin; ADVANCE();
        const float* pB = pin; ADVANCE();
        const float* pC = pin; ADVANCE();
        f3 PA = *reinterpret_cast<const f3*>(pA);
        f3 PB = *reinterpret_cast<const f3*>(pB);
        f3 PC = *reinterpret_cast<const f3*>(pC);

        COMPUTE_STORE(PA, pout);
        COMPUTE_STORE(PB, pout + STEP_OUT);
        COMPUTE_STORE(PC, pout + 2 * STEP_OUT);
        pout += 3 * STEP_OUT;
    }
#undef ADVANCE
#undef COMPUTE_STORE
}

extern "C" void kernel_launch(void* const* d_in, const int* in_sizes, int n_in,
                              void* d_out, int out_size, void* d_ws, size_t ws_size,
                              hipStream_t stream) {
    const float* x     = (const float*)d_in[0];
    const float* w_enc = (const float*)d_in[1];
    const float* a_rz  = (const float*)d_in[2];
    const float* b_ry  = (const float*)d_in[3];
    float* out = (float*)d_out;

    int block = 256;
    int grid = GTHREADS / block;   // 3969
    qconv_fused<<<grid, block, 0, stream>>>(x, w_enc, a_rz, b_ry, out);
}